// Round 1
// baseline (4586.724 us; speedup 1.0000x reference)
//
#include <hip/hip_runtime.h>
#include <math.h>

#define B_   8
#define T_   1024
#define K_   76
#define H_   8
#define D_   6
#define C_   2
#define HK_  608   // H*K
#define F_   304   // 4*K
#define BT_  8192  // B*T
#define EPS_ 1e-5f
#define SCALE_ 0.1147078669352809f  // 1/sqrt(76)

// ---------------- embedding: tokens = concat(4 linears) + pos ----------------
__global__ void embed_kernel(const float* __restrict__ v, const float* __restrict__ x,
                             const float* __restrict__ y, const float* __restrict__ z,
                             const float* __restrict__ W_hp, const float* __restrict__ b_hp,
                             const float* __restrict__ W_lm, const float* __restrict__ b_lm,
                             const float* __restrict__ W_el, const float* __restrict__ b_el,
                             const float* __restrict__ W_au, const float* __restrict__ b_au,
                             const float* __restrict__ pos, float* __restrict__ h) {
  int idx = blockIdx.x * 256 + threadIdx.x;
  if (idx >= BT_ * K_) return;
  int bt = idx / K_, c = idx % K_;
  int t = bt % T_;
  float acc;
  if (c < 6) {
    acc = b_hp[c];
    const float* vr = v + bt * 6;
    #pragma unroll
    for (int i = 0; i < 6; i++) acc += vr[i] * W_hp[i * 6 + c];
  } else if (c < 36) {
    int cc = c - 6; acc = b_lm[cc];
    const float* xr = x + bt * 137;
    for (int i = 0; i < 137; i++) acc += xr[i] * W_lm[i * 30 + cc];
  } else if (c < 66) {
    int cc = c - 36; acc = b_el[cc];
    const float* yr = y + bt * 113;
    for (int i = 0; i < 113; i++) acc += yr[i] * W_el[i * 30 + cc];
  } else {
    int cc = c - 66; acc = b_au[cc];
    const float* zr = z + bt * 35;
    for (int i = 0; i < 35; i++) acc += zr[i] * W_au[i * 10 + cc];
  }
  h[idx] = acc + pos[t * K_ + c];
}

// ---------------- generic GEMM: C[8192 x N] = A[8192 x Kd] @ W[Kd x N] (+bias)(+relu) ----
// BM=64, BN=64, BK=32; 256 threads, 4x4 micro-tile.
template<int RELU>
__global__ __launch_bounds__(256) void gemm_kernel(const float* __restrict__ A,
                                                   const float* __restrict__ W,
                                                   const float* __restrict__ bias,
                                                   float* __restrict__ C,
                                                   int Kd, int N) {
  __shared__ float As[64][36];   // row stride 144B: 16B aligned; rows 4 apart -> 2 bank-sets
  __shared__ float Bs[32][68];   // row stride 272B: 16B aligned; per-lane b128 contiguous
  int n0 = blockIdx.x * 64;
  int m0 = blockIdx.y * 64;
  int tid = threadIdx.x;
  int tx = tid & 15, ty = tid >> 4;
  float acc[4][4] = {};
  for (int k0 = 0; k0 < Kd; k0 += 32) {
    int kw = Kd - k0; if (kw > 32) kw = 32;   // always a multiple of 4 for Kd in {76,304,608}
    __syncthreads();
    for (int i = tid; i < 64 * 32; i += 256) {
      int r = i >> 5, kk = i & 31;
      As[r][kk] = (kk < kw) ? A[(m0 + r) * Kd + k0 + kk] : 0.f;
    }
    for (int i = tid; i < 32 * 64; i += 256) {
      int kk = i >> 6, n = i & 63;
      float val = 0.f;
      if (kk < kw && (n0 + n) < N) val = W[(k0 + kk) * N + n0 + n];
      Bs[kk][n] = val;
    }
    __syncthreads();
    int nk4 = kw >> 2;
    for (int k4 = 0; k4 < nk4; k4++) {
      float4 a4[4];
      #pragma unroll
      for (int i = 0; i < 4; i++) a4[i] = *(const float4*)&As[ty * 4 + i][k4 * 4];
      float4 b0 = *(const float4*)&Bs[k4 * 4 + 0][tx * 4];
      float4 b1 = *(const float4*)&Bs[k4 * 4 + 1][tx * 4];
      float4 b2 = *(const float4*)&Bs[k4 * 4 + 2][tx * 4];
      float4 b3 = *(const float4*)&Bs[k4 * 4 + 3][tx * 4];
      #pragma unroll
      for (int i = 0; i < 4; i++) {
        acc[i][0] += a4[i].x * b0.x + a4[i].y * b1.x + a4[i].z * b2.x + a4[i].w * b3.x;
        acc[i][1] += a4[i].x * b0.y + a4[i].y * b1.y + a4[i].z * b2.y + a4[i].w * b3.y;
        acc[i][2] += a4[i].x * b0.z + a4[i].y * b1.z + a4[i].z * b2.z + a4[i].w * b3.z;
        acc[i][3] += a4[i].x * b0.w + a4[i].y * b1.w + a4[i].z * b2.w + a4[i].w * b3.w;
      }
    }
  }
  #pragma unroll
  for (int i = 0; i < 4; i++) {
    int row = m0 + ty * 4 + i;
    #pragma unroll
    for (int j = 0; j < 4; j++) {
      int col = n0 + tx * 4 + j;
      if (col < N) {
        float val = acc[i][j];
        if (bias) val += bias[col];
        if (RELU) val = fmaxf(val, 0.f);
        C[row * N + col] = val;
      }
    }
  }
}

// ---------------- flash attention (fp32): per (b, h, 64-row q-tile) ----------------
__global__ __launch_bounds__(256) void attn_kernel(const float* __restrict__ q,
                                                   const float* __restrict__ k,
                                                   const float* __restrict__ v,
                                                   float* __restrict__ att) {
  __shared__ float Qs[64][84];   // q rows (stride 336B)
  __shared__ float Kt[76][68];   // K transposed: [e][k-col] (stride 272B)
  __shared__ float Vt[76][68];   // V transposed: [e][k-row]
  __shared__ float Ss[64][68];   // P tile
  int qt = blockIdx.x;   // 0..15
  int hh = blockIdx.y;   // 0..7
  int b  = blockIdx.z;   // 0..7
  int tid = threadIdx.x;
  int tx = tid & 15, ty = tid >> 4;
  int qbase = b * T_ + qt * 64;
  int hoff = hh * K_;

  for (int i = tid; i < 64 * 76; i += 256) {
    int r = i / 76, e = i % 76;
    Qs[r][e] = q[(qbase + r) * HK_ + hoff + e];
  }

  float mstat[4], lstat[4], o[4][5];
  #pragma unroll
  for (int i = 0; i < 4; i++) {
    mstat[i] = -INFINITY; lstat[i] = 0.f;
    #pragma unroll
    for (int jc = 0; jc < 5; jc++) o[i][jc] = 0.f;
  }

  for (int kt = 0; kt < 16; kt++) {
    __syncthreads();   // previous PV / Ss reads complete
    int kbase = b * T_ + kt * 64;
    for (int i = tid; i < 64 * 76; i += 256) {
      int r = i / 76, e = i % 76;
      Kt[e][r] = k[(kbase + r) * HK_ + hoff + e];
      Vt[e][r] = v[(kbase + r) * HK_ + hoff + e];
    }
    __syncthreads();

    // S = Q @ K^T * scale
    float s[4][4] = {};
    for (int k4 = 0; k4 < 19; k4++) {
      float4 a4[4];
      #pragma unroll
      for (int i = 0; i < 4; i++) a4[i] = *(const float4*)&Qs[ty * 4 + i][k4 * 4];
      float4 b0 = *(const float4*)&Kt[k4 * 4 + 0][tx * 4];
      float4 b1 = *(const float4*)&Kt[k4 * 4 + 1][tx * 4];
      float4 b2 = *(const float4*)&Kt[k4 * 4 + 2][tx * 4];
      float4 b3 = *(const float4*)&Kt[k4 * 4 + 3][tx * 4];
      #pragma unroll
      for (int i = 0; i < 4; i++) {
        s[i][0] += a4[i].x * b0.x + a4[i].y * b1.x + a4[i].z * b2.x + a4[i].w * b3.x;
        s[i][1] += a4[i].x * b0.y + a4[i].y * b1.y + a4[i].z * b2.y + a4[i].w * b3.y;
        s[i][2] += a4[i].x * b0.z + a4[i].y * b1.z + a4[i].z * b2.z + a4[i].w * b3.z;
        s[i][3] += a4[i].x * b0.w + a4[i].y * b1.w + a4[i].z * b2.w + a4[i].w * b3.w;
      }
    }

    // online softmax (row stats replicated across the 16 tx lanes of each row group)
    #pragma unroll
    for (int i = 0; i < 4; i++) {
      float s0 = s[i][0] * SCALE_, s1 = s[i][1] * SCALE_,
            s2 = s[i][2] * SCALE_, s3 = s[i][3] * SCALE_;
      float rmax = fmaxf(fmaxf(s0, s1), fmaxf(s2, s3));
      rmax = fmaxf(rmax, __shfl_xor(rmax, 1));
      rmax = fmaxf(rmax, __shfl_xor(rmax, 2));
      rmax = fmaxf(rmax, __shfl_xor(rmax, 4));
      rmax = fmaxf(rmax, __shfl_xor(rmax, 8));
      float newm = fmaxf(mstat[i], rmax);
      float p0 = __expf(s0 - newm), p1 = __expf(s1 - newm),
            p2 = __expf(s2 - newm), p3 = __expf(s3 - newm);
      float rsum = p0 + p1 + p2 + p3;
      rsum += __shfl_xor(rsum, 1);
      rsum += __shfl_xor(rsum, 2);
      rsum += __shfl_xor(rsum, 4);
      rsum += __shfl_xor(rsum, 8);
      float alpha = __expf(mstat[i] - newm);
      lstat[i] = lstat[i] * alpha + rsum;
      mstat[i] = newm;
      #pragma unroll
      for (int jc = 0; jc < 5; jc++) o[i][jc] *= alpha;
      Ss[ty * 4 + i][tx * 4 + 0] = p0;
      Ss[ty * 4 + i][tx * 4 + 1] = p1;
      Ss[ty * 4 + i][tx * 4 + 2] = p2;
      Ss[ty * 4 + i][tx * 4 + 3] = p3;
    }
    __syncthreads();

    // O += P @ V    (o cols: c = jc*16 + tx)
    for (int k4 = 0; k4 < 16; k4++) {
      float4 p4[4];
      #pragma unroll
      for (int i = 0; i < 4; i++) p4[i] = *(const float4*)&Ss[ty * 4 + i][k4 * 4];
      #pragma unroll
      for (int jc = 0; jc < 5; jc++) {
        int c = jc * 16 + tx;
        const float4 v4 = *(const float4*)&Vt[(c < 76) ? c : 0][k4 * 4];
        #pragma unroll
        for (int i = 0; i < 4; i++)
          o[i][jc] += p4[i].x * v4.x + p4[i].y * v4.y + p4[i].z * v4.z + p4[i].w * v4.w;
      }
    }
  }

  #pragma unroll
  for (int i = 0; i < 4; i++) {
    float inv = 1.f / lstat[i];
    int row = qbase + ty * 4 + i;
    #pragma unroll
    for (int jc = 0; jc < 5; jc++) {
      int c = jc * 16 + tx;
      if (c < 76) att[row * HK_ + hoff + c] = o[i][jc] * inv;
    }
  }
}

// ---------------- fused residual + LayerNorm over 76 dims (one wave per row) ----------
__global__ __launch_bounds__(256) void ln_kernel(const float* __restrict__ xin,
                                                 const float* __restrict__ res,
                                                 const float* __restrict__ sc,
                                                 const float* __restrict__ bb,
                                                 float* __restrict__ out) {
  int w = threadIdx.x >> 6, lane = threadIdx.x & 63;
  int row = blockIdx.x * 4 + w;
  const float* xr = xin + row * K_;
  const float* rr = res + row * K_;
  float v0 = xr[lane] + rr[lane];
  float v1 = (lane < 12) ? (xr[64 + lane] + rr[64 + lane]) : 0.f;
  float sum = v0 + v1;
  #pragma unroll
  for (int m = 1; m < 64; m <<= 1) sum += __shfl_xor(sum, m);
  float mu = sum * (1.f / 76.f);
  float d0 = v0 - mu;
  float d1 = (lane < 12) ? (v1 - mu) : 0.f;
  float var = d0 * d0 + d1 * d1;
  #pragma unroll
  for (int m = 1; m < 64; m <<= 1) var += __shfl_xor(var, m);
  float rstd = rsqrtf(var * (1.f / 76.f) + EPS_);
  out[row * K_ + lane] = d0 * rstd * sc[lane] + bb[lane];
  if (lane < 12) out[row * K_ + 64 + lane] = d1 * rstd * sc[64 + lane] + bb[64 + lane];
}

// ---------------- output projection (K=76 -> C=2) ----------------
__global__ void out_kernel(const float* __restrict__ h, const float* __restrict__ W,
                           const float* __restrict__ bias, float* __restrict__ out) {
  int idx = blockIdx.x * 256 + threadIdx.x;
  if (idx >= BT_ * C_) return;
  int bt = idx >> 1, c = idx & 1;
  float acc = bias[c];
  const float* hr = h + bt * K_;
  #pragma unroll 4
  for (int e = 0; e < K_; e++) acc += hr[e] * W[e * C_ + c];
  out[idx] = acc;
}

extern "C" void kernel_launch(void* const* d_in, const int* in_sizes, int n_in,
                              void* d_out, int out_size, void* d_ws, size_t ws_size,
                              hipStream_t stream) {
  const float* v    = (const float*)d_in[0];
  const float* x    = (const float*)d_in[1];
  const float* y    = (const float*)d_in[2];
  const float* z    = (const float*)d_in[3];
  const float* W_hp = (const float*)d_in[4];
  const float* b_hp = (const float*)d_in[5];
  const float* W_lm = (const float*)d_in[6];
  const float* b_lm = (const float*)d_in[7];
  const float* W_el = (const float*)d_in[8];
  const float* b_el = (const float*)d_in[9];
  const float* W_au = (const float*)d_in[10];
  const float* b_au = (const float*)d_in[11];
  const float* pos  = (const float*)d_in[12];
  const float* Wq   = (const float*)d_in[13];
  const float* Wk   = (const float*)d_in[14];
  const float* Wv   = (const float*)d_in[15];
  const float* Wu   = (const float*)d_in[16];
  const float* bu   = (const float*)d_in[17];
  const float* ln1s = (const float*)d_in[18];
  const float* ln1b = (const float*)d_in[19];
  const float* W1   = (const float*)d_in[20];
  const float* b1   = (const float*)d_in[21];
  const float* W2   = (const float*)d_in[22];
  const float* b2   = (const float*)d_in[23];
  const float* ln2s = (const float*)d_in[24];
  const float* ln2b = (const float*)d_in[25];
  const float* Wout = (const float*)d_in[26];
  const float* bout = (const float*)d_in[27];

  float* ws  = (float*)d_ws;
  float* h   = ws;                 // 8192*76
  float* qb  = h  + BT_ * K_;      // 8192*608
  float* kb  = qb + BT_ * HK_;     // 8192*608
  float* vb  = kb + BT_ * HK_;     // 8192*608
  float* att = vb + BT_ * HK_;     // 8192*608
  // dead-buffer aliases:
  float* u  = qb;   // att@Wu+bu   (q dead after attention)
  float* h1 = kb;   // LN1 out     (k dead after attention)
  float* ff = vb;   // relu ffn    (v dead after attention)
  float* f2 = qb;   // ffn out     (u dead after LN1)

  embed_kernel<<<(BT_ * K_ + 255) / 256, 256, 0, stream>>>(
      v, x, y, z, W_hp, b_hp, W_lm, b_lm, W_el, b_el, W_au, b_au, pos, h);

  for (int d = 0; d < D_; d++) {
    const float* Wq_d = Wq + (size_t)d * K_ * HK_;
    const float* Wk_d = Wk + (size_t)d * K_ * HK_;
    const float* Wv_d = Wv + (size_t)d * K_ * HK_;
    const float* Wu_d = Wu + (size_t)d * HK_ * K_;
    const float* bu_d = bu + (size_t)d * K_;
    const float* l1s  = ln1s + (size_t)d * K_;
    const float* l1b  = ln1b + (size_t)d * K_;
    const float* W1_d = W1 + (size_t)d * K_ * F_;
    const float* b1_d = b1 + (size_t)d * F_;
    const float* W2_d = W2 + (size_t)d * F_ * K_;
    const float* b2_d = b2 + (size_t)d * K_;
    const float* l2s  = ln2s + (size_t)d * K_;
    const float* l2b  = ln2b + (size_t)d * K_;

    dim3 gqkv(10, 128);
    gemm_kernel<0><<<gqkv, 256, 0, stream>>>(h, Wq_d, nullptr, qb, K_, HK_);
    gemm_kernel<0><<<gqkv, 256, 0, stream>>>(h, Wk_d, nullptr, kb, K_, HK_);
    gemm_kernel<0><<<gqkv, 256, 0, stream>>>(h, Wv_d, nullptr, vb, K_, HK_);

    attn_kernel<<<dim3(16, 8, 8), 256, 0, stream>>>(qb, kb, vb, att);

    gemm_kernel<0><<<dim3(2, 128), 256, 0, stream>>>(att, Wu_d, bu_d, u, HK_, K_);
    ln_kernel<<<BT_ / 4, 256, 0, stream>>>(u, h, l1s, l1b, h1);
    gemm_kernel<1><<<dim3(5, 128), 256, 0, stream>>>(h1, W1_d, b1_d, ff, K_, F_);
    gemm_kernel<0><<<dim3(2, 128), 256, 0, stream>>>(ff, W2_d, b2_d, f2, F_, K_);
    ln_kernel<<<BT_ / 4, 256, 0, stream>>>(f2, h1, l2s, l2b, h);
  }

  out_kernel<<<(BT_ * C_ + 255) / 256, 256, 0, stream>>>(h, Wout, bout, (float*)d_out);
}

// Round 2
// 1197.245 us; speedup vs baseline: 3.8311x; 3.8311x over previous
//
#include <hip/hip_runtime.h>
#include <hip/hip_bf16.h>
#include <math.h>

#define B_   8
#define T_   1024
#define K_   76
#define KP_  96      // padded model dim (3 x 32)
#define H_   8
#define D_   6
#define C_   2
#define HK_  608     // H*K
#define FF_  304     // 4*K
#define FFP_ 320     // padded FF (10 x 32)
#define BT_  8192
#define EPS_ 1e-5f

typedef unsigned short u16;
typedef short bf16x8 __attribute__((ext_vector_type(8)));
typedef float f32x4 __attribute__((ext_vector_type(4)));

__device__ __forceinline__ u16 f2b(float f) {
  __hip_bfloat16 h = __float2bfloat16(f);
  return *reinterpret_cast<u16*>(&h);
}
__device__ __forceinline__ float b2f(u16 u) {
  __hip_bfloat16 h = *reinterpret_cast<__hip_bfloat16*>(&u);
  return __bfloat162float(h);
}

// =================== weight convert+transpose: fp32 [Kd][N] -> bf16 [Nalloc][Kp] ===========
#define PER_L_ 304128ULL   // per-layer u16 elems: 3*640*96 + 96*608 + 320*96 + 96*320
__global__ __launch_bounds__(256) void wconv_kernel(
    const float* __restrict__ Wq, const float* __restrict__ Wk, const float* __restrict__ Wv,
    const float* __restrict__ Wu, const float* __restrict__ W1, const float* __restrict__ W2,
    u16* __restrict__ WT) {
  __shared__ float Ls[32][65];
  int zz = blockIdx.y;               // 0..35 -> (layer d, weight type)
  int d = zz / 6, wt = zz % 6;
  const float* in; int Kd, N, Nalloc, Kp; u16* out;
  size_t lb = (size_t)d * PER_L_;
  switch (wt) {
    case 0: in = Wq + (size_t)d*K_*HK_; Kd=K_;  N=HK_; Nalloc=640; Kp=KP_;  out = WT + lb;          break;
    case 1: in = Wk + (size_t)d*K_*HK_; Kd=K_;  N=HK_; Nalloc=640; Kp=KP_;  out = WT + lb + 61440;  break;
    case 2: in = Wv + (size_t)d*K_*HK_; Kd=K_;  N=HK_; Nalloc=640; Kp=KP_;  out = WT + lb + 122880; break;
    case 3: in = Wu + (size_t)d*HK_*K_; Kd=HK_; N=K_;  Nalloc=96;  Kp=HK_;  out = WT + lb + 184320; break;
    case 4: in = W1 + (size_t)d*K_*FF_; Kd=K_;  N=FF_; Nalloc=320; Kp=KP_;  out = WT + lb + 242688; break;
    default:in = W2 + (size_t)d*FF_*K_; Kd=FF_; N=K_;  Nalloc=96;  Kp=FFP_; out = WT + lb + 273408; break;
  }
  int tiles_k = Kp / 32;
  int tiles_n = (Nalloc + 63) / 64;
  int tile = blockIdx.x;
  if (tile >= tiles_k * tiles_n) return;
  int tn = tile / tiles_k, tk = tile % tiles_k;
  int n0 = tn * 64, k0 = tk * 32;
  for (int i = threadIdx.x; i < 2048; i += 256) {
    int kk = i >> 6, nn = i & 63;
    int gk = k0 + kk, gn = n0 + nn;
    Ls[kk][nn] = (gk < Kd && gn < N) ? in[(size_t)gk * N + gn] : 0.f;
  }
  __syncthreads();
  for (int i = threadIdx.x; i < 2048; i += 256) {
    int nn = i >> 5, kk = i & 31;
    int gn = n0 + nn;
    if (gn < Nalloc) out[(size_t)gn * Kp + k0 + kk] = f2b(Ls[kk][nn]);
  }
}

// =================== embedding -> bf16 h[8192][96] (zero-padded) ===========
__global__ void embed_kernel(const float* __restrict__ v, const float* __restrict__ x,
                             const float* __restrict__ y, const float* __restrict__ z,
                             const float* __restrict__ W_hp, const float* __restrict__ b_hp,
                             const float* __restrict__ W_lm, const float* __restrict__ b_lm,
                             const float* __restrict__ W_el, const float* __restrict__ b_el,
                             const float* __restrict__ W_au, const float* __restrict__ b_au,
                             const float* __restrict__ pos, u16* __restrict__ h) {
  int idx = blockIdx.x * 256 + threadIdx.x;
  if (idx >= BT_ * KP_) return;
  int bt = idx / KP_, c = idx % KP_;
  if (c >= K_) { h[idx] = 0; return; }
  int t = bt % T_;
  float acc;
  if (c < 6) {
    acc = b_hp[c];
    const float* vr = v + bt * 6;
    #pragma unroll
    for (int i = 0; i < 6; i++) acc += vr[i] * W_hp[i * 6 + c];
  } else if (c < 36) {
    int cc = c - 6; acc = b_lm[cc];
    const float* xr = x + bt * 137;
    for (int i = 0; i < 137; i++) acc += xr[i] * W_lm[i * 30 + cc];
  } else if (c < 66) {
    int cc = c - 36; acc = b_el[cc];
    const float* yr = y + bt * 113;
    for (int i = 0; i < 113; i++) acc += yr[i] * W_el[i * 30 + cc];
  } else {
    int cc = c - 66; acc = b_au[cc];
    const float* zr = z + bt * 35;
    for (int i = 0; i < 35; i++) acc += zr[i] * W_au[i * 10 + cc];
  }
  h[idx] = f2b(acc + pos[t * K_ + c]);
}

// =================== MFMA GEMM: C[8192 x N] = A[8192 x K] @ WT^T, WT = [Nalloc][Kp] bf16 ====
// RT row-tiles per wave (BM = 64*RT), CT col-tiles (BN = 16*CT), KSTEPS k-steps of 32.
// z-dim: weight select (wstride) + split-K (k0 = z*ksplit) + output select (osplit).
template<int RT, int CT, int KSTEPS, int RELU>
__global__ __launch_bounds__(256) void gemm_kernel(
    const u16* __restrict__ A, int lda,
    const u16* __restrict__ Wt, int ldw, unsigned long long wstride,
    const float* __restrict__ bias,
    u16* __restrict__ Cc, int ldc, int N,
    int ksplit, int klen, unsigned long long osplit) {
  __shared__ u16 Bs[CT * 16][40];
  const int tid = threadIdx.x;
  const int w = tid >> 6, lane = tid & 63;
  const int r = lane & 15, g = lane >> 4;
  const int n0 = blockIdx.x * CT * 16;
  const int m0 = blockIdx.y * 64 * RT;
  const int z = blockIdx.z;
  const int k0 = z * ksplit;
  const int kend = k0 + klen;
  const u16* Wz = Wt + (size_t)z * wstride;
  const float* bias_eff = (z == 0) ? bias : nullptr;
  u16* Cz = Cc + (size_t)z * osplit;

  const f32x4 fz = {0.f, 0.f, 0.f, 0.f};
  f32x4 acc[RT][CT];
  #pragma unroll
  for (int rt = 0; rt < RT; rt++)
    #pragma unroll
    for (int ct = 0; ct < CT; ct++) acc[rt][ct] = fz;

  const u16* arow[RT];
  #pragma unroll
  for (int rt = 0; rt < RT; rt++)
    arow[rt] = A + (size_t)(m0 + (w * RT + rt) * 16 + r) * lda;

  for (int ks = 0; ks < KSTEPS; ks++) {
    int kk = k0 + ks * 32;
    for (int i = tid; i < CT * 16 * 4; i += 256) {
      int nn = i >> 2, kc = i & 3;
      ushort4 lo = make_ushort4(0, 0, 0, 0), hi = make_ushort4(0, 0, 0, 0);
      if (kk + kc * 8 < kend) {
        const u16* p = Wz + (size_t)(n0 + nn) * ldw + kk + kc * 8;
        lo = *(const ushort4*)p;
        hi = *(const ushort4*)(p + 4);
      }
      *(ushort4*)&Bs[nn][kc * 8] = lo;
      *(ushort4*)&Bs[nn][kc * 8 + 4] = hi;
    }
    __syncthreads();
    bf16x8 a_[RT];
    #pragma unroll
    for (int rt = 0; rt < RT; rt++) {
      int kA = kk + g * 8;
      if (kA < kend) a_[rt] = *(const bf16x8*)(arow[rt] + kA);
      else a_[rt] = bf16x8{0, 0, 0, 0, 0, 0, 0, 0};
    }
    #pragma unroll
    for (int ct = 0; ct < CT; ct++) {
      bf16x8 bb = *(const bf16x8*)&Bs[ct * 16 + r][g * 8];
      #pragma unroll
      for (int rt = 0; rt < RT; rt++)
        acc[rt][ct] = __builtin_amdgcn_mfma_f32_16x16x32_bf16(a_[rt], bb, acc[rt][ct], 0, 0, 0);
    }
    __syncthreads();
  }
  #pragma unroll
  for (int rt = 0; rt < RT; rt++) {
    #pragma unroll
    for (int ct = 0; ct < CT; ct++) {
      int col = n0 + ct * 16 + r;
      if (col < ldc) {
        #pragma unroll
        for (int reg = 0; reg < 4; reg++) {
          int row = m0 + (w * RT + rt) * 16 + g * 4 + reg;
          float val = acc[rt][ct][reg];
          if (bias_eff && col < N) val += bias_eff[col];
          if (RELU) val = fmaxf(val, 0.f);
          Cz[(size_t)row * ldc + col] = f2b(val);
        }
      }
    }
  }
}

// =================== flash attention, bf16 MFMA ===========
__global__ __launch_bounds__(256) void attn_kernel(const u16* __restrict__ q,
                                                   const u16* __restrict__ k,
                                                   const u16* __restrict__ v,
                                                   u16* __restrict__ att) {
  __shared__ u16 Qs[64][104];   // 208B stride: 16B-aligned, 2-way bank period
  __shared__ u16 Ks[64][104];
  __shared__ u16 Vt[80][88];    // V transposed: [feature][kv-row], 176B stride
  __shared__ u16 Ps[64][88];    // P tile (per-wave-private 16-row strips)
  const int qt = blockIdx.x, hh = blockIdx.y, b = blockIdx.z;
  const int tid = threadIdx.x;
  const int w = tid >> 6, lane = tid & 63;
  const int r = lane & 15, g = lane >> 4;
  const int qbase = b * T_ + qt * 64;
  const int hoff = hh * K_;
  const float SCL2 = 0.11470786693528088f * 1.4426950408889634f;  // 1/sqrt(76) * log2(e)

  {  // stage Q (64 x 96, zero-padded cols 76..95)
    const int row = tid & 63, qq = tid >> 6;
    const u16* src = q + (size_t)(qbase + row) * HK_ + hoff;
    #pragma unroll
    for (int i = 0; i < 3; i++) {
      int e0 = (qq + 4 * i) * 8;
      ushort4 lo = make_ushort4(0, 0, 0, 0), hi = make_ushort4(0, 0, 0, 0);
      if (e0 < 72) { lo = *(const ushort4*)(src + e0); hi = *(const ushort4*)(src + e0 + 4); }
      else if (e0 == 72) { lo = *(const ushort4*)(src + e0); }
      *(ushort4*)&Qs[row][e0] = lo;
      *(ushort4*)&Qs[row][e0 + 4] = hi;
    }
  }
  __syncthreads();
  bf16x8 aq[3];
  #pragma unroll
  for (int ks = 0; ks < 3; ks++)
    aq[ks] = *(const bf16x8*)&Qs[w * 16 + r][ks * 32 + g * 8];

  const f32x4 fz = {0.f, 0.f, 0.f, 0.f};
  f32x4 o[5];
  float m2[4], lsum[4];
  #pragma unroll
  for (int i = 0; i < 5; i++) o[i] = fz;
  #pragma unroll
  for (int i = 0; i < 4; i++) { m2[i] = -INFINITY; lsum[i] = 0.f; }

  for (int kt = 0; kt < 16; kt++) {
    __syncthreads();
    {  // stage K (row-major, padded) and V (transposed)
      const int row = tid & 63, qq = tid >> 6;
      const int kbase = b * T_ + kt * 64;
      const u16* ksrc = k + (size_t)(kbase + row) * HK_ + hoff;
      const u16* vsrc = v + (size_t)(kbase + row) * HK_ + hoff;
      #pragma unroll
      for (int i = 0; i < 3; i++) {
        int e0 = (qq + 4 * i) * 8;
        ushort4 lo = make_ushort4(0, 0, 0, 0), hi = make_ushort4(0, 0, 0, 0);
        if (e0 < 72) { lo = *(const ushort4*)(ksrc + e0); hi = *(const ushort4*)(ksrc + e0 + 4); }
        else if (e0 == 72) { lo = *(const ushort4*)(ksrc + e0); }
        *(ushort4*)&Ks[row][e0] = lo;
        *(ushort4*)&Ks[row][e0 + 4] = hi;
        if (e0 < 80) {   // V: features 0..79 only (76..79 zeroed)
          ushort4 vlo = make_ushort4(0, 0, 0, 0), vhi = make_ushort4(0, 0, 0, 0);
          if (e0 < 72) { vlo = *(const ushort4*)(vsrc + e0); vhi = *(const ushort4*)(vsrc + e0 + 4); }
          else { vlo = *(const ushort4*)(vsrc + e0); }
          Vt[e0 + 0][row] = vlo.x; Vt[e0 + 1][row] = vlo.y;
          Vt[e0 + 2][row] = vlo.z; Vt[e0 + 3][row] = vlo.w;
          Vt[e0 + 4][row] = vhi.x; Vt[e0 + 5][row] = vhi.y;
          Vt[e0 + 6][row] = vhi.z; Vt[e0 + 7][row] = vhi.w;
        }
      }
    }
    __syncthreads();
    // S = Q @ K^T  (wave strip: 16 rows x 64 kv-cols)
    f32x4 s[4];
    #pragma unroll
    for (int ct = 0; ct < 4; ct++) {
      s[ct] = fz;
      #pragma unroll
      for (int ks = 0; ks < 3; ks++) {
        bf16x8 bk = *(const bf16x8*)&Ks[ct * 16 + r][ks * 32 + g * 8];
        s[ct] = __builtin_amdgcn_mfma_f32_16x16x32_bf16(aq[ks], bk, s[ct], 0, 0, 0);
      }
    }
    // online softmax in exp2 domain; lane owns rows 4g+reg, cols 16ct+r
    #pragma unroll
    for (int reg = 0; reg < 4; reg++) {
      float s0 = s[0][reg] * SCL2, s1 = s[1][reg] * SCL2,
            s2 = s[2][reg] * SCL2, s3 = s[3][reg] * SCL2;
      float mx = fmaxf(fmaxf(s0, s1), fmaxf(s2, s3));
      mx = fmaxf(mx, __shfl_xor(mx, 1));
      mx = fmaxf(mx, __shfl_xor(mx, 2));
      mx = fmaxf(mx, __shfl_xor(mx, 4));
      mx = fmaxf(mx, __shfl_xor(mx, 8));
      float nm = fmaxf(m2[reg], mx);
      float p0 = exp2f(s0 - nm), p1 = exp2f(s1 - nm),
            p2 = exp2f(s2 - nm), p3 = exp2f(s3 - nm);
      float rs = p0 + p1 + p2 + p3;
      rs += __shfl_xor(rs, 1);
      rs += __shfl_xor(rs, 2);
      rs += __shfl_xor(rs, 4);
      rs += __shfl_xor(rs, 8);
      float alpha = exp2f(m2[reg] - nm);
      lsum[reg] = lsum[reg] * alpha + rs;
      m2[reg] = nm;
      #pragma unroll
      for (int c5 = 0; c5 < 5; c5++) o[c5][reg] *= alpha;
      int prow = w * 16 + g * 4 + reg;
      Ps[prow][r] = f2b(p0);
      Ps[prow][16 + r] = f2b(p1);
      Ps[prow][32 + r] = f2b(p2);
      Ps[prow][48 + r] = f2b(p3);
    }
    // O += P @ V
    #pragma unroll
    for (int ks = 0; ks < 2; ks++) {
      bf16x8 pa = *(const bf16x8*)&Ps[w * 16 + r][ks * 32 + g * 8];
      #pragma unroll
      for (int c5 = 0; c5 < 5; c5++) {
        bf16x8 bv = *(const bf16x8*)&Vt[c5 * 16 + r][ks * 32 + g * 8];
        o[c5] = __builtin_amdgcn_mfma_f32_16x16x32_bf16(pa, bv, o[c5], 0, 0, 0);
      }
    }
  }
  #pragma unroll
  for (int reg = 0; reg < 4; reg++) {
    float inv = 1.f / lsum[reg];
    int row = qbase + w * 16 + g * 4 + reg;
    #pragma unroll
    for (int c5 = 0; c5 < 5; c5++) {
      int col = c5 * 16 + r;
      if (col < K_) att[(size_t)row * HK_ + hoff + col] = f2b(o[c5][reg] * inv);
    }
  }
}

// =================== fused (x0 + x1 + res) + LayerNorm -> bf16 (zero-padded) ===========
__global__ __launch_bounds__(256) void ln_kernel(const u16* __restrict__ x0,
                                                 const u16* __restrict__ x1,
                                                 const u16* __restrict__ res,
                                                 const float* __restrict__ sc,
                                                 const float* __restrict__ bb,
                                                 u16* __restrict__ out) {
  int w = threadIdx.x >> 6, lane = threadIdx.x & 63;
  int row = blockIdx.x * 4 + w;
  size_t base = (size_t)row * KP_;
  float v0 = b2f(x0[base + lane]) + b2f(x1[base + lane]) + b2f(res[base + lane]);
  float v1 = 0.f;
  if (lane < 12) {
    int c = 64 + lane;
    v1 = b2f(x0[base + c]) + b2f(x1[base + c]) + b2f(res[base + c]);
  }
  float sum = v0 + v1;
  #pragma unroll
  for (int m = 1; m < 64; m <<= 1) sum += __shfl_xor(sum, m);
  float mu = sum * (1.f / 76.f);
  float d0 = v0 - mu;
  float d1 = (lane < 12) ? (v1 - mu) : 0.f;
  float var = d0 * d0 + d1 * d1;
  #pragma unroll
  for (int m = 1; m < 64; m <<= 1) var += __shfl_xor(var, m);
  float rstd = rsqrtf(var * (1.f / 76.f) + EPS_);
  out[base + lane] = f2b(d0 * rstd * sc[lane] + bb[lane]);
  if (lane < 32) {
    int c = 64 + lane;
    float val = (lane < 12) ? (d1 * rstd * sc[c] + bb[c]) : 0.f;
    out[base + c] = f2b(val);
  }
}

// =================== output projection 76 -> 2, fp32 out ===========
__global__ void out_kernel(const u16* __restrict__ h, const float* __restrict__ W,
                           const float* __restrict__ bias, float* __restrict__ out) {
  int idx = blockIdx.x * 256 + threadIdx.x;
  if (idx >= BT_ * C_) return;
  int bt = idx >> 1, c = idx & 1;
  float acc = bias[c];
  const u16* hr = h + (size_t)bt * KP_;
  #pragma unroll 4
  for (int e = 0; e < K_; e++) acc += b2f(hr[e]) * W[e * C_ + c];
  out[idx] = acc;
}

extern "C" void kernel_launch(void* const* d_in, const int* in_sizes, int n_in,
                              void* d_out, int out_size, void* d_ws, size_t ws_size,
                              hipStream_t stream) {
  const float* v    = (const float*)d_in[0];
  const float* x    = (const float*)d_in[1];
  const float* y    = (const float*)d_in[2];
  const float* z    = (const float*)d_in[3];
  const float* W_hp = (const float*)d_in[4];
  const float* b_hp = (const float*)d_in[5];
  const float* W_lm = (const float*)d_in[6];
  const float* b_lm = (const float*)d_in[7];
  const float* W_el = (const float*)d_in[8];
  const float* b_el = (const float*)d_in[9];
  const float* W_au = (const float*)d_in[10];
  const float* b_au = (const float*)d_in[11];
  const float* pos  = (const float*)d_in[12];
  const float* Wq   = (const float*)d_in[13];
  const float* Wk   = (const float*)d_in[14];
  const float* Wv   = (const float*)d_in[15];
  const float* Wu   = (const float*)d_in[16];
  const float* bu   = (const float*)d_in[17];
  const float* ln1s = (const float*)d_in[18];
  const float* ln1b = (const float*)d_in[19];
  const float* W1   = (const float*)d_in[20];
  const float* b1   = (const float*)d_in[21];
  const float* W2   = (const float*)d_in[22];
  const float* b2   = (const float*)d_in[23];
  const float* ln2s = (const float*)d_in[24];
  const float* ln2b = (const float*)d_in[25];
  const float* Wout = (const float*)d_in[26];
  const float* bout = (const float*)d_in[27];

  u16* ws = (u16*)d_ws;
  u16* WT  = ws;                         // 6 * 304128
  u16* h   = WT + 6 * PER_L_;            // 8192*96
  u16* qb  = h + 786432;                 // 8192*608
  u16* kb  = qb + 4980736;
  u16* vb  = kb + 4980736;
  u16* att = vb + 4980736;
  u16* u0  = att + 4980736;              // 8192*96
  u16* u1  = u0 + 786432;
  u16* h1  = u1 + 786432;
  u16* ff  = h1 + 786432;                // 8192*320
  u16* f20 = ff + 2621440;
  u16* f21 = f20 + 786432;

  wconv_kernel<<<dim3(38, 36), 256, 0, stream>>>(Wq, Wk, Wv, Wu, W1, W2, WT);
  embed_kernel<<<(BT_ * KP_ + 255) / 256, 256, 0, stream>>>(
      v, x, y, z, W_hp, b_hp, W_lm, b_lm, W_el, b_el, W_au, b_au, pos, h);

  for (int d = 0; d < D_; d++) {
    u16* WTd = WT + (size_t)d * PER_L_;
    const float* bu_d = bu + (size_t)d * K_;
    const float* l1s  = ln1s + (size_t)d * K_;
    const float* l1b  = ln1b + (size_t)d * K_;
    const float* b1_d = b1 + (size_t)d * FF_;
    const float* b2_d = b2 + (size_t)d * K_;
    const float* l2s  = ln2s + (size_t)d * K_;
    const float* l2b  = ln2b + (size_t)d * K_;

    // QKV: z selects weight (wstride) and output (osplit)
    gemm_kernel<2, 5, 3, 0><<<dim3(8, 64, 3), 256, 0, stream>>>(
        h, KP_, WTd, KP_, 61440ULL, nullptr, qb, HK_, HK_, 0, KP_, 4980736ULL);
    attn_kernel<<<dim3(16, 8, 8), 256, 0, stream>>>(qb, kb, vb, att);
    // Wu: split-K=2 over 608 -> u0,u1
    gemm_kernel<1, 6, 10, 0><<<dim3(1, 128, 2), 256, 0, stream>>>(
        att, HK_, WTd + 184320, HK_, 0ULL, bu_d, u0, KP_, K_, 304, 304, 786432ULL);
    ln_kernel<<<BT_ / 4, 256, 0, stream>>>(u0, u1, h, l1s, l1b, h1);
    // W1 (+relu)
    gemm_kernel<2, 5, 3, 1><<<dim3(4, 64, 1), 256, 0, stream>>>(
        h1, KP_, WTd + 242688, KP_, 0ULL, b1_d, ff, FFP_, FF_, 0, KP_, 0ULL);
    // W2: split-K=2 over 320 -> f20,f21
    gemm_kernel<1, 6, 5, 0><<<dim3(1, 128, 2), 256, 0, stream>>>(
        ff, FFP_, WTd + 273408, FFP_, 0ULL, b2_d, f20, KP_, K_, 160, 160, 786432ULL);
    ln_kernel<<<BT_ / 4, 256, 0, stream>>>(f20, f21, h1, l2s, l2b, h);
  }

  out_kernel<<<(BT_ * C_ + 255) / 256, 256, 0, stream>>>(h, Wout, bout, (float*)d_out);
}

// Round 3
// 800.799 us; speedup vs baseline: 5.7277x; 1.4951x over previous
//
#include <hip/hip_runtime.h>
#include <hip/hip_bf16.h>
#include <math.h>

#define B_   8
#define T_   1024
#define K_   76
#define KP_  96      // padded model dim (3 x 32)
#define H_   8
#define D_   6
#define C_   2
#define HK_  608     // H*K
#define FF_  304     // 4*K
#define FFP_ 320     // padded FF (10 x 32)
#define BT_  8192
#define EPS_ 1e-5f

typedef unsigned short u16;
typedef short bf16x8 __attribute__((ext_vector_type(8)));
typedef float f32x4 __attribute__((ext_vector_type(4)));

__device__ __forceinline__ u16 f2b(float f) {
  __hip_bfloat16 h = __float2bfloat16(f);
  return *reinterpret_cast<u16*>(&h);
}
__device__ __forceinline__ float b2f(u16 u) {
  __hip_bfloat16 h = *reinterpret_cast<__hip_bfloat16*>(&u);
  return __bfloat162float(h);
}

union V8U {
  ushort4 u4[2];
  bf16x8 v8;
};

// masked 8-u16 chunk load from a 76-element row (e0 multiple of 8)
__device__ __forceinline__ void load_chunk76(const u16* __restrict__ src, int e0,
                                             ushort4& lo, ushort4& hi) {
  lo = make_ushort4(0, 0, 0, 0);
  hi = make_ushort4(0, 0, 0, 0);
  if (e0 + 8 <= K_) {
    lo = *(const ushort4*)(src + e0);
    hi = *(const ushort4*)(src + e0 + 4);
  } else if (e0 < K_) {          // e0 == 72: feats 72..75 valid
    lo = *(const ushort4*)(src + e0);
  }
}

// swizzled LDS index: row stride 104 u16 (52 dw, mod32=20 -> 8 bank groups);
// 16B chunk XOR'd with row&3 spreads the 4 g-chunks (T2 recipe).
__device__ __forceinline__ int kidx(int row, int col) {
  return row * 104 + ((((col >> 3) ^ (row & 3)) << 3) | (col & 7));
}

// =================== weight convert+transpose: fp32 [Kd][N] -> bf16 [Nalloc][Kp] ===========
#define PER_L_ 304128ULL
__global__ __launch_bounds__(256) void wconv_kernel(
    const float* __restrict__ Wq, const float* __restrict__ Wk, const float* __restrict__ Wv,
    const float* __restrict__ Wu, const float* __restrict__ W1, const float* __restrict__ W2,
    u16* __restrict__ WT) {
  __shared__ float Ls[32][65];
  int zz = blockIdx.y;
  int d = zz / 6, wt = zz % 6;
  const float* in; int Kd, N, Nalloc, Kp; u16* out;
  size_t lb = (size_t)d * PER_L_;
  switch (wt) {
    case 0: in = Wq + (size_t)d*K_*HK_; Kd=K_;  N=HK_; Nalloc=640; Kp=KP_;  out = WT + lb;          break;
    case 1: in = Wk + (size_t)d*K_*HK_; Kd=K_;  N=HK_; Nalloc=640; Kp=KP_;  out = WT + lb + 61440;  break;
    case 2: in = Wv + (size_t)d*K_*HK_; Kd=K_;  N=HK_; Nalloc=640; Kp=KP_;  out = WT + lb + 122880; break;
    case 3: in = Wu + (size_t)d*HK_*K_; Kd=HK_; N=K_;  Nalloc=96;  Kp=HK_;  out = WT + lb + 184320; break;
    case 4: in = W1 + (size_t)d*K_*FF_; Kd=K_;  N=FF_; Nalloc=320; Kp=KP_;  out = WT + lb + 242688; break;
    default:in = W2 + (size_t)d*FF_*K_; Kd=FF_; N=K_;  Nalloc=96;  Kp=FFP_; out = WT + lb + 273408; break;
  }
  int tiles_k = Kp / 32;
  int tiles_n = (Nalloc + 63) / 64;
  int tile = blockIdx.x;
  if (tile >= tiles_k * tiles_n) return;
  int tn = tile / tiles_k, tk = tile % tiles_k;
  int n0 = tn * 64, k0 = tk * 32;
  for (int i = threadIdx.x; i < 2048; i += 256) {
    int kk = i >> 6, nn = i & 63;
    int gk = k0 + kk, gn = n0 + nn;
    Ls[kk][nn] = (gk < Kd && gn < N) ? in[(size_t)gk * N + gn] : 0.f;
  }
  __syncthreads();
  for (int i = threadIdx.x; i < 2048; i += 256) {
    int nn = i >> 5, kk = i & 31;
    int gn = n0 + nn;
    if (gn < Nalloc) out[(size_t)gn * Kp + k0 + kk] = f2b(Ls[kk][nn]);
  }
}

// =================== embedding -> bf16 h[8192][96] ===========
__global__ void embed_kernel(const float* __restrict__ v, const float* __restrict__ x,
                             const float* __restrict__ y, const float* __restrict__ z,
                             const float* __restrict__ W_hp, const float* __restrict__ b_hp,
                             const float* __restrict__ W_lm, const float* __restrict__ b_lm,
                             const float* __restrict__ W_el, const float* __restrict__ b_el,
                             const float* __restrict__ W_au, const float* __restrict__ b_au,
                             const float* __restrict__ pos, u16* __restrict__ h) {
  int idx = blockIdx.x * 256 + threadIdx.x;
  if (idx >= BT_ * KP_) return;
  int bt = idx / KP_, c = idx % KP_;
  if (c >= K_) { h[idx] = 0; return; }
  int t = bt % T_;
  float acc;
  if (c < 6) {
    acc = b_hp[c];
    const float* vr = v + bt * 6;
    #pragma unroll
    for (int i = 0; i < 6; i++) acc += vr[i] * W_hp[i * 6 + c];
  } else if (c < 36) {
    int cc = c - 6; acc = b_lm[cc];
    const float* xr = x + bt * 137;
    for (int i = 0; i < 137; i++) acc += xr[i] * W_lm[i * 30 + cc];
  } else if (c < 66) {
    int cc = c - 36; acc = b_el[cc];
    const float* yr = y + bt * 113;
    for (int i = 0; i < 113; i++) acc += yr[i] * W_el[i * 30 + cc];
  } else {
    int cc = c - 66; acc = b_au[cc];
    const float* zr = z + bt * 35;
    for (int i = 0; i < 35; i++) acc += zr[i] * W_au[i * 10 + cc];
  }
  h[idx] = f2b(acc + pos[t * K_ + c]);
}

// =================== MFMA GEMM with swizzled Bs + A-hoist + B-prefetch ====
template<int RT, int CT, int KSTEPS, int RELU>
__global__ __launch_bounds__(256) void gemm_kernel(
    const u16* __restrict__ A, int lda,
    const u16* __restrict__ Wt, int ldw, unsigned long long wstride,
    const float* __restrict__ bias,
    u16* __restrict__ Cc, int ldc, int N,
    int ksplit, int klen, unsigned long long osplit) {
  __shared__ u16 Bs[CT * 16 * 56];   // stride 56 u16 (28 dw) + chunk XOR swizzle
  const int tid = threadIdx.x;
  const int w = tid >> 6, lane = tid & 63;
  const int r = lane & 15, g = lane >> 4;
  const int n0 = blockIdx.x * CT * 16;
  const int m0 = blockIdx.y * 64 * RT;
  const int z = blockIdx.z;
  const int k0 = z * ksplit;
  const int kend = k0 + klen;
  const u16* Wz = Wt + (size_t)z * wstride;
  const float* bias_eff = (z == 0) ? bias : nullptr;
  u16* Cz = Cc + (size_t)z * osplit;
  constexpr int NB = (CT * 64 + 255) / 256;   // B-stage units per thread

  const f32x4 fz = {0.f, 0.f, 0.f, 0.f};
  f32x4 acc[RT][CT];
  #pragma unroll
  for (int rt = 0; rt < RT; rt++)
    #pragma unroll
    for (int ct = 0; ct < CT; ct++) acc[rt][ct] = fz;

  // hoist all A fragments (removes global latency from the k-loop)
  bf16x8 a_all[RT][KSTEPS];
  #pragma unroll
  for (int rt = 0; rt < RT; rt++) {
    const u16* arow = A + (size_t)(m0 + (w * RT + rt) * 16 + r) * lda;
    #pragma unroll
    for (int ks = 0; ks < KSTEPS; ks++) {
      int kA = k0 + ks * 32 + g * 8;
      if (kA < kend) a_all[rt][ks] = *(const bf16x8*)(arow + kA);
      else a_all[rt][ks] = bf16x8{0, 0, 0, 0, 0, 0, 0, 0};
    }
  }

  // B prefetch regs
  uint4 bpre[NB];
  auto loadB = [&](int ks) {
    int kk = k0 + ks * 32;
    #pragma unroll
    for (int i0 = 0; i0 < NB; i0++) {
      int idx = tid + i0 * 256;
      bpre[i0] = make_uint4(0, 0, 0, 0);
      if (idx < CT * 64) {
        int nn = idx >> 2, kc = idx & 3;
        if (kk + kc * 8 < kend)
          bpre[i0] = *(const uint4*)(Wz + (size_t)(n0 + nn) * ldw + kk + kc * 8);
      }
    }
  };
  loadB(0);

  for (int ks = 0; ks < KSTEPS; ks++) {
    __syncthreads();
    #pragma unroll
    for (int i0 = 0; i0 < NB; i0++) {
      int idx = tid + i0 * 256;
      if (idx < CT * 64) {
        int nn = idx >> 2, kc = idx & 3;
        *(uint4*)&Bs[nn * 56 + (((kc ^ (nn & 3)) << 3))] = bpre[i0];
      }
    }
    __syncthreads();
    if (ks + 1 < KSTEPS) loadB(ks + 1);
    #pragma unroll
    for (int ct = 0; ct < CT; ct++) {
      bf16x8 bb = *(const bf16x8*)&Bs[(ct * 16 + r) * 56 + (((g ^ (r & 3)) << 3))];
      #pragma unroll
      for (int rt = 0; rt < RT; rt++)
        acc[rt][ct] = __builtin_amdgcn_mfma_f32_16x16x32_bf16(a_all[rt][ks], bb, acc[rt][ct], 0, 0, 0);
    }
  }
  #pragma unroll
  for (int rt = 0; rt < RT; rt++) {
    #pragma unroll
    for (int ct = 0; ct < CT; ct++) {
      int col = n0 + ct * 16 + r;
      if (col < ldc) {
        #pragma unroll
        for (int reg = 0; reg < 4; reg++) {
          int row = m0 + (w * RT + rt) * 16 + g * 4 + reg;
          float val = acc[rt][ct][reg];
          if (bias_eff && col < N) val += bias_eff[col];
          if (RELU) val = fmaxf(val, 0.f);
          Cz[(size_t)row * ldc + col] = f2b(val);
        }
      }
    }
  }
}

// =================== flash attention: 128 q-rows/block, swizzled LDS, T14 prefetch ===========
__global__ __launch_bounds__(256, 2) void attn_kernel(const u16* __restrict__ q,
                                                      const u16* __restrict__ k,
                                                      const u16* __restrict__ v,
                                                      u16* __restrict__ att) {
  __shared__ u16 Ks[64 * 104];    // K tile: [kv 64][feat 96pad]
  __shared__ u16 Vt[90 * 104];    // V^T: phys row = feat + feat/8 (skewed), col = kv
  __shared__ u16 Ps[128 * 104];   // P: [q-row 128][kv 64], wave-private strips
  const int qt = blockIdx.x, hh = blockIdx.y, b = blockIdx.z;
  const int tid = threadIdx.x;
  const int w = tid >> 6, lane = tid & 63;
  const int r = lane & 15, g = lane >> 4;
  const int qbase = b * T_ + qt * 128;
  const int hoff = hh * K_;
  const float SCL2 = 0.11470786693528088f * 1.4426950408889634f;  // 1/sqrt(76)*log2(e)

  // ---- Q fragments direct from global (masked at feat>=76) ----
  bf16x8 aq[2][3];
  #pragma unroll
  for (int rt = 0; rt < 2; rt++) {
    const u16* src = q + (size_t)(qbase + w * 32 + rt * 16 + r) * HK_ + hoff;
    #pragma unroll
    for (int ks = 0; ks < 3; ks++) {
      V8U t;
      load_chunk76(src, ks * 32 + g * 8, t.u4[0], t.u4[1]);
      aq[rt][ks] = t.v8;
    }
  }

  // ---- staging-prefetch register sets ----
  const int krow = tid >> 2, kq4 = tid & 3;          // K: row 0..63, chunk group
  const int vpA = tid >> 3, vfA = tid & 7;           // V phase A: kvpair, fchunk 0..7
  const int vpB = tid >> 1, vfB = 8 + (tid & 1);     // V phase B (tid<64): fchunk 8,9
  ushort4 kpre[3][2];
  ushort4 vpreA[2][2], vpreB[2][2];

  auto stage_load = [&](int kt) {
    int kbase = b * T_ + kt * 64;
    const u16* ksrc = k + (size_t)(kbase + krow) * HK_ + hoff;
    #pragma unroll
    for (int i = 0; i < 3; i++)
      load_chunk76(ksrc, (kq4 + 4 * i) * 8, kpre[i][0], kpre[i][1]);
    const u16* vsrc = v + (size_t)(kbase + 2 * vpA) * HK_ + hoff;
    load_chunk76(vsrc, vfA * 8, vpreA[0][0], vpreA[0][1]);
    load_chunk76(vsrc + HK_, vfA * 8, vpreA[1][0], vpreA[1][1]);
    if (tid < 64) {
      const u16* vsrc2 = v + (size_t)(kbase + 2 * vpB) * HK_ + hoff;
      load_chunk76(vsrc2, vfB * 8, vpreB[0][0], vpreB[0][1]);
      load_chunk76(vsrc2 + HK_, vfB * 8, vpreB[1][0], vpreB[1][1]);
    }
  };

  auto vt_write8 = [&](int f, int kv0, ushort4 aLo, ushort4 aHi, ushort4 bLo, ushort4 bHi) {
    u16 a8[8] = {aLo.x, aLo.y, aLo.z, aLo.w, aHi.x, aHi.y, aHi.z, aHi.w};
    u16 b8[8] = {bLo.x, bLo.y, bLo.z, bLo.w, bHi.x, bHi.y, bHi.z, bHi.w};
    #pragma unroll
    for (int i = 0; i < 8; i++) {
      int feat = f * 8 + i;
      int vr = feat + f;                        // phys skew: feat + feat/8
      unsigned val = (unsigned)a8[i] | ((unsigned)b8[i] << 16);
      *(unsigned*)&Vt[kidx(vr, kv0)] = val;
    }
  };

  auto stage_write = [&]() {
    #pragma unroll
    for (int i = 0; i < 3; i++) {
      int c = kq4 + 4 * i;
      int idx = krow * 104 + ((c ^ (krow & 3)) << 3);
      *(ushort4*)&Ks[idx] = kpre[i][0];
      *(ushort4*)&Ks[idx + 4] = kpre[i][1];
    }
    vt_write8(vfA, 2 * vpA, vpreA[0][0], vpreA[0][1], vpreA[1][0], vpreA[1][1]);
    if (tid < 64)
      vt_write8(vfB, 2 * vpB, vpreB[0][0], vpreB[0][1], vpreB[1][0], vpreB[1][1]);
  };

  const f32x4 fz = {0.f, 0.f, 0.f, 0.f};
  f32x4 o[2][5];
  float m2[2][4], ls[2][4];
  #pragma unroll
  for (int rt = 0; rt < 2; rt++) {
    #pragma unroll
    for (int i = 0; i < 5; i++) o[rt][i] = fz;
    #pragma unroll
    for (int i = 0; i < 4; i++) { m2[rt][i] = -INFINITY; ls[rt][i] = 0.f; }
  }

  stage_load(0);
  for (int kt = 0; kt < 16; kt++) {
    __syncthreads();          // previous tile's LDS reads done
    stage_write();
    __syncthreads();
    if (kt < 15) stage_load(kt + 1);   // overlaps with compute below (T14)

    // ---- S = Q K^T ----
    f32x4 s[2][4];
    #pragma unroll
    for (int ct = 0; ct < 4; ct++) { s[0][ct] = fz; s[1][ct] = fz; }
    #pragma unroll
    for (int ct = 0; ct < 4; ct++) {
      #pragma unroll
      for (int ks = 0; ks < 3; ks++) {
        bf16x8 bk = *(const bf16x8*)&Ks[(ct * 16 + r) * 104 + (((ks * 4 + g) ^ (r & 3)) << 3)];
        s[0][ct] = __builtin_amdgcn_mfma_f32_16x16x32_bf16(aq[0][ks], bk, s[0][ct], 0, 0, 0);
        s[1][ct] = __builtin_amdgcn_mfma_f32_16x16x32_bf16(aq[1][ks], bk, s[1][ct], 0, 0, 0);
      }
    }

    // ---- online softmax (exp2 domain), P -> Ps ----
    #pragma unroll
    for (int rt = 0; rt < 2; rt++) {
      #pragma unroll
      for (int reg = 0; reg < 4; reg++) {
        float s0 = s[rt][0][reg] * SCL2, s1 = s[rt][1][reg] * SCL2,
              s2 = s[rt][2][reg] * SCL2, s3 = s[rt][3][reg] * SCL2;
        float mx = fmaxf(fmaxf(s0, s1), fmaxf(s2, s3));
        mx = fmaxf(mx, __shfl_xor(mx, 1));
        mx = fmaxf(mx, __shfl_xor(mx, 2));
        mx = fmaxf(mx, __shfl_xor(mx, 4));
        mx = fmaxf(mx, __shfl_xor(mx, 8));
        float nm = fmaxf(m2[rt][reg], mx);
        float p0 = exp2f(s0 - nm), p1 = exp2f(s1 - nm),
              p2 = exp2f(s2 - nm), p3 = exp2f(s3 - nm);
        float rs = p0 + p1 + p2 + p3;
        rs += __shfl_xor(rs, 1);
        rs += __shfl_xor(rs, 2);
        rs += __shfl_xor(rs, 4);
        rs += __shfl_xor(rs, 8);
        float alpha = exp2f(m2[rt][reg] - nm);
        ls[rt][reg] = ls[rt][reg] * alpha + rs;
        m2[rt][reg] = nm;
        #pragma unroll
        for (int c5 = 0; c5 < 5; c5++) o[rt][c5][reg] *= alpha;
        int prow = w * 32 + rt * 16 + g * 4 + reg;
        int pbase = prow * 104;
        int sw = prow & 3;
        Ps[pbase + ((((0 + (r >> 3)) ^ sw) << 3) | (r & 7))] = f2b(p0);
        Ps[pbase + ((((2 + (r >> 3)) ^ sw) << 3) | (r & 7))] = f2b(p1);
        Ps[pbase + ((((4 + (r >> 3)) ^ sw) << 3) | (r & 7))] = f2b(p2);
        Ps[pbase + ((((6 + (r >> 3)) ^ sw) << 3) | (r & 7))] = f2b(p3);
      }
    }

    // ---- O += P V ---- (Ps rows are wave-private; in-wave lgkmcnt ordering suffices)
    #pragma unroll
    for (int ks = 0; ks < 2; ks++) {
      bf16x8 pa[2];
      #pragma unroll
      for (int rt = 0; rt < 2; rt++) {
        int prow = w * 32 + rt * 16 + r;
        pa[rt] = *(const bf16x8*)&Ps[prow * 104 + (((ks * 4 + g) ^ (r & 3)) << 3)];
      }
      #pragma unroll
      for (int c5 = 0; c5 < 5; c5++) {
        int feat = c5 * 16 + r;
        int vr = feat + (feat >> 3);
        bf16x8 bv = *(const bf16x8*)&Vt[vr * 104 + (((ks * 4 + g) ^ (vr & 3)) << 3)];
        #pragma unroll
        for (int rt = 0; rt < 2; rt++)
          o[rt][c5] = __builtin_amdgcn_mfma_f32_16x16x32_bf16(pa[rt], bv, o[rt][c5], 0, 0, 0);
      }
    }
  }

  #pragma unroll
  for (int rt = 0; rt < 2; rt++) {
    #pragma unroll
    for (int reg = 0; reg < 4; reg++) {
      float inv = 1.f / ls[rt][reg];
      int row = qbase + w * 32 + rt * 16 + g * 4 + reg;
      #pragma unroll
      for (int c5 = 0; c5 < 5; c5++) {
        int col = c5 * 16 + r;
        if (col < K_) att[(size_t)row * HK_ + hoff + col] = f2b(o[rt][c5][reg] * inv);
      }
    }
  }
}

// =================== fused (x0 + x1 + res) + LayerNorm -> bf16 ===========
__global__ __launch_bounds__(256) void ln_kernel(const u16* __restrict__ x0,
                                                 const u16* __restrict__ x1,
                                                 const u16* __restrict__ res,
                                                 const float* __restrict__ sc,
                                                 const float* __restrict__ bb,
                                                 u16* __restrict__ out) {
  int w = threadIdx.x >> 6, lane = threadIdx.x & 63;
  int row = blockIdx.x * 4 + w;
  size_t base = (size_t)row * KP_;
  float v0 = b2f(x0[base + lane]) + b2f(x1[base + lane]) + b2f(res[base + lane]);
  float v1 = 0.f;
  if (lane < 12) {
    int c = 64 + lane;
    v1 = b2f(x0[base + c]) + b2f(x1[base + c]) + b2f(res[base + c]);
  }
  float sum = v0 + v1;
  #pragma unroll
  for (int m = 1; m < 64; m <<= 1) sum += __shfl_xor(sum, m);
  float mu = sum * (1.f / 76.f);
  float d0 = v0 - mu;
  float d1 = (lane < 12) ? (v1 - mu) : 0.f;
  float var = d0 * d0 + d1 * d1;
  #pragma unroll
  for (int m = 1; m < 64; m <<= 1) var += __shfl_xor(var, m);
  float rstd = rsqrtf(var * (1.f / 76.f) + EPS_);
  out[base + lane] = f2b(d0 * rstd * sc[lane] + bb[lane]);
  if (lane < 32) {
    int c = 64 + lane;
    float val = (lane < 12) ? (d1 * rstd * sc[c] + bb[c]) : 0.f;
    out[base + c] = f2b(val);
  }
}

// =================== output projection 76 -> 2, fp32 out ===========
__global__ void out_kernel(const u16* __restrict__ h, const float* __restrict__ W,
                           const float* __restrict__ bias, float* __restrict__ out) {
  int idx = blockIdx.x * 256 + threadIdx.x;
  if (idx >= BT_ * C_) return;
  int bt = idx >> 1, c = idx & 1;
  float acc = bias[c];
  const u16* hr = h + (size_t)bt * KP_;
  #pragma unroll 4
  for (int e = 0; e < K_; e++) acc += b2f(hr[e]) * W[e * C_ + c];
  out[idx] = acc;
}

extern "C" void kernel_launch(void* const* d_in, const int* in_sizes, int n_in,
                              void* d_out, int out_size, void* d_ws, size_t ws_size,
                              hipStream_t stream) {
  const float* v    = (const float*)d_in[0];
  const float* x    = (const float*)d_in[1];
  const float* y    = (const float*)d_in[2];
  const float* z    = (const float*)d_in[3];
  const float* W_hp = (const float*)d_in[4];
  const float* b_hp = (const float*)d_in[5];
  const float* W_lm = (const float*)d_in[6];
  const float* b_lm = (const float*)d_in[7];
  const float* W_el = (const float*)d_in[8];
  const float* b_el = (const float*)d_in[9];
  const float* W_au = (const float*)d_in[10];
  const float* b_au = (const float*)d_in[11];
  const float* pos  = (const float*)d_in[12];
  const float* Wq   = (const float*)d_in[13];
  const float* Wk   = (const float*)d_in[14];
  const float* Wv   = (const float*)d_in[15];
  const float* Wu   = (const float*)d_in[16];
  const float* bu   = (const float*)d_in[17];
  const float* ln1s = (const float*)d_in[18];
  const float* ln1b = (const float*)d_in[19];
  const float* W1   = (const float*)d_in[20];
  const float* b1   = (const float*)d_in[21];
  const float* W2   = (const float*)d_in[22];
  const float* b2   = (const float*)d_in[23];
  const float* ln2s = (const float*)d_in[24];
  const float* ln2b = (const float*)d_in[25];
  const float* Wout = (const float*)d_in[26];
  const float* bout = (const float*)d_in[27];

  u16* ws = (u16*)d_ws;
  u16* WT  = ws;                         // 6 * 304128
  u16* h   = WT + 6 * PER_L_;            // 8192*96
  u16* qb  = h + 786432;                 // 8192*608
  u16* kb  = qb + 4980736;
  u16* vb  = kb + 4980736;
  u16* att = vb + 4980736;
  u16* u0  = att + 4980736;              // 8192*96
  u16* u1  = u0 + 786432;
  u16* h1  = u1 + 786432;
  u16* ff  = h1 + 786432;                // 8192*320
  u16* f20 = ff + 2621440;
  u16* f21 = f20 + 786432;

  wconv_kernel<<<dim3(38, 36), 256, 0, stream>>>(Wq, Wk, Wv, Wu, W1, W2, WT);
  embed_kernel<<<(BT_ * KP_ + 255) / 256, 256, 0, stream>>>(
      v, x, y, z, W_hp, b_hp, W_lm, b_lm, W_el, b_el, W_au, b_au, pos, h);

  for (int d = 0; d < D_; d++) {
    u16* WTd = WT + (size_t)d * PER_L_;
    const float* bu_d = bu + (size_t)d * K_;
    const float* l1s  = ln1s + (size_t)d * K_;
    const float* l1b  = ln1b + (size_t)d * K_;
    const float* b1_d = b1 + (size_t)d * FF_;
    const float* b2_d = b2 + (size_t)d * K_;
    const float* l2s  = ln2s + (size_t)d * K_;
    const float* l2b  = ln2b + (size_t)d * K_;

    // QKV: z selects weight (wstride) and output (osplit)
    gemm_kernel<2, 5, 3, 0><<<dim3(8, 64, 3), 256, 0, stream>>>(
        h, KP_, WTd, KP_, 61440ULL, nullptr, qb, HK_, HK_, 0, KP_, 4980736ULL);
    attn_kernel<<<dim3(8, 8, 8), 256, 0, stream>>>(qb, kb, vb, att);
    // Wu: split-K=2 over 608 -> u0,u1
    gemm_kernel<1, 6, 10, 0><<<dim3(1, 128, 2), 256, 0, stream>>>(
        att, HK_, WTd + 184320, HK_, 0ULL, bu_d, u0, KP_, K_, 304, 304, 786432ULL);
    ln_kernel<<<BT_ / 4, 256, 0, stream>>>(u0, u1, h, l1s, l1b, h1);
    // W1 (+relu)
    gemm_kernel<2, 5, 3, 1><<<dim3(4, 64, 1), 256, 0, stream>>>(
        h1, KP_, WTd + 242688, KP_, 0ULL, b1_d, ff, FFP_, FF_, 0, KP_, 0ULL);
    // W2: split-K=2 over 320 -> f20,f21
    gemm_kernel<1, 6, 5, 0><<<dim3(1, 128, 2), 256, 0, stream>>>(
        ff, FFP_, WTd + 273408, FFP_, 0ULL, b2_d, f20, KP_, K_, 160, 160, 786432ULL);
    ln_kernel<<<BT_ / 4, 256, 0, stream>>>(f20, f21, h1, l2s, l2b, h);
  }

  out_kernel<<<(BT_ * C_ + 255) / 256, 256, 0, stream>>>(h, Wout, bout, (float*)d_out);
}

// Round 4
// 794.929 us; speedup vs baseline: 5.7700x; 1.0074x over previous
//
#include <hip/hip_runtime.h>
#include <hip/hip_bf16.h>
#include <math.h>

#define B_   8
#define T_   1024
#define K_   76
#define KP_  96      // padded model dim (3 x 32)
#define H_   8
#define D_   6
#define C_   2
#define HK_  608     // H*K (packed att layout)
#define QKLD_ 640    // q/k row stride: 8 heads x 80
#define FF_  304     // 4*K
#define FFP_ 320     // padded FF
#define BT_  8192
#define EPS_ 1e-5f

typedef unsigned short u16;
typedef unsigned int u32;
typedef short bf16x8 __attribute__((ext_vector_type(8)));
typedef float f32x4 __attribute__((ext_vector_type(4)));

__device__ __forceinline__ u16 f2b(float f) {
  __hip_bfloat16 h = __float2bfloat16(f);
  return *reinterpret_cast<u16*>(&h);
}
__device__ __forceinline__ float b2f(u16 u) {
  __hip_bfloat16 h = *reinterpret_cast<__hip_bfloat16*>(&u);
  return __bfloat162float(h);
}
__device__ __forceinline__ u32 pack2(float a, float b) {
  __hip_bfloat162 t = __float22bfloat162_rn(make_float2(a, b));
  return *reinterpret_cast<u32*>(&t);
}

// swizzled LDS index for Ks (stride 104 u16): 16B chunk XOR'd with row&3
__device__ __forceinline__ int kidx(int row, int col) {
  return row * 104 + ((((col >> 3) ^ (row & 3)) << 3) | (col & 7));
}

// =================== weight convert+transpose ===========
// QKV (wt<3): fp32 [76][608] -> bf16 [640][96]: out col n' = hh*80+ft (ft<76 from src, else 0)
// Wu: [608][76] -> [96][608]; W1: [76][304] -> [320][96]; W2: [304][76] -> [96][320]
#define PER_L_ 304128ULL
__global__ __launch_bounds__(256) void wconv_kernel(
    const float* __restrict__ Wq, const float* __restrict__ Wk, const float* __restrict__ Wv,
    const float* __restrict__ Wu, const float* __restrict__ W1, const float* __restrict__ W2,
    u16* __restrict__ WT) {
  __shared__ float Ls[32][65];
  int zz = blockIdx.y;
  int d = zz / 6, wt = zz % 6;
  const float* in; int Kd, Nsrc, Nalloc, Kp; u16* out;
  size_t lb = (size_t)d * PER_L_;
  switch (wt) {
    case 0: in = Wq + (size_t)d*K_*HK_; Kd=K_;  Nsrc=HK_; Nalloc=640; Kp=KP_;  out = WT + lb;          break;
    case 1: in = Wk + (size_t)d*K_*HK_; Kd=K_;  Nsrc=HK_; Nalloc=640; Kp=KP_;  out = WT + lb + 61440;  break;
    case 2: in = Wv + (size_t)d*K_*HK_; Kd=K_;  Nsrc=HK_; Nalloc=640; Kp=KP_;  out = WT + lb + 122880; break;
    case 3: in = Wu + (size_t)d*HK_*K_; Kd=HK_; Nsrc=K_;  Nalloc=96;  Kp=HK_;  out = WT + lb + 184320; break;
    case 4: in = W1 + (size_t)d*K_*FF_; Kd=K_;  Nsrc=FF_; Nalloc=320; Kp=KP_;  out = WT + lb + 242688; break;
    default:in = W2 + (size_t)d*FF_*K_; Kd=FF_; Nsrc=K_;  Nalloc=96;  Kp=FFP_; out = WT + lb + 273408; break;
  }
  int tiles_k = Kp / 32;
  int tiles_n = (Nalloc + 63) / 64;
  int tile = blockIdx.x;
  if (tile >= tiles_k * tiles_n) return;
  int tn = tile / tiles_k, tk = tile % tiles_k;
  int n0 = tn * 64, k0 = tk * 32;
  for (int i = threadIdx.x; i < 2048; i += 256) {
    int kk = i >> 6, nn = i & 63;
    int gk = k0 + kk, gn = n0 + nn;
    int srccol = gn;
    if (wt < 3) {
      int hh8 = gn / 80, ft = gn - hh8 * 80;
      srccol = (ft < 76) ? (hh8 * 76 + ft) : -1;
    }
    Ls[kk][nn] = (gk < Kd && srccol >= 0 && srccol < Nsrc) ? in[(size_t)gk * Nsrc + srccol] : 0.f;
  }
  __syncthreads();
  for (int i = threadIdx.x; i < 2048; i += 256) {
    int nn = i >> 5, kk = i & 31;
    int gn = n0 + nn;
    if (gn < Nalloc) out[(size_t)gn * Kp + k0 + kk] = f2b(Ls[kk][nn]);
  }
}

// =================== embedding -> bf16 h[8192][96] ===========
__global__ void embed_kernel(const float* __restrict__ v, const float* __restrict__ x,
                             const float* __restrict__ y, const float* __restrict__ z,
                             const float* __restrict__ W_hp, const float* __restrict__ b_hp,
                             const float* __restrict__ W_lm, const float* __restrict__ b_lm,
                             const float* __restrict__ W_el, const float* __restrict__ b_el,
                             const float* __restrict__ W_au, const float* __restrict__ b_au,
                             const float* __restrict__ pos, u16* __restrict__ h) {
  int idx = blockIdx.x * 256 + threadIdx.x;
  if (idx >= BT_ * KP_) return;
  int bt = idx / KP_, c = idx % KP_;
  if (c >= K_) { h[idx] = 0; return; }
  int t = bt % T_;
  float acc;
  if (c < 6) {
    acc = b_hp[c];
    const float* vr = v + bt * 6;
    #pragma unroll
    for (int i = 0; i < 6; i++) acc += vr[i] * W_hp[i * 6 + c];
  } else if (c < 36) {
    int cc = c - 6; acc = b_lm[cc];
    const float* xr = x + bt * 137;
    for (int i = 0; i < 137; i++) acc += xr[i] * W_lm[i * 30 + cc];
  } else if (c < 66) {
    int cc = c - 36; acc = b_el[cc];
    const float* yr = y + bt * 113;
    for (int i = 0; i < 113; i++) acc += yr[i] * W_el[i * 30 + cc];
  } else {
    int cc = c - 66; acc = b_au[cc];
    const float* zr = z + bt * 35;
    for (int i = 0; i < 35; i++) acc += zr[i] * W_au[i * 10 + cc];
  }
  h[idx] = f2b(acc + pos[t * K_ + c]);
}

// =================== MFMA GEMM (optional V-transposed epilogue for z==2) ====
template<int RT, int CT, int KSTEPS, int RELU>
__global__ __launch_bounds__(256) void gemm_kernel(
    const u16* __restrict__ A, int lda,
    const u16* __restrict__ Wt, int ldw, unsigned long long wstride,
    const float* __restrict__ bias,
    u16* __restrict__ Cc, int ldc, int N,
    int ksplit, int klen, unsigned long long osplit,
    u16* __restrict__ vbt) {
  __shared__ u16 Bs[CT * 16 * 56];
  const int tid = threadIdx.x;
  const int w = tid >> 6, lane = tid & 63;
  const int r = lane & 15, g = lane >> 4;
  const int n0 = blockIdx.x * CT * 16;
  const int m0 = blockIdx.y * 64 * RT;
  const int z = blockIdx.z;
  const int k0 = z * ksplit;
  const int kend = k0 + klen;
  const u16* Wz = Wt + (size_t)z * wstride;
  const float* bias_eff = (z == 0) ? bias : nullptr;
  u16* Cz = Cc + (size_t)z * osplit;
  constexpr int NB = (CT * 64 + 255) / 256;

  const f32x4 fz = {0.f, 0.f, 0.f, 0.f};
  f32x4 acc[RT][CT];
  #pragma unroll
  for (int rt = 0; rt < RT; rt++)
    #pragma unroll
    for (int ct = 0; ct < CT; ct++) acc[rt][ct] = fz;

  bf16x8 a_all[RT][KSTEPS];
  #pragma unroll
  for (int rt = 0; rt < RT; rt++) {
    const u16* arow = A + (size_t)(m0 + (w * RT + rt) * 16 + r) * lda;
    #pragma unroll
    for (int ks = 0; ks < KSTEPS; ks++) {
      int kA = k0 + ks * 32 + g * 8;
      if (kA < kend) a_all[rt][ks] = *(const bf16x8*)(arow + kA);
      else a_all[rt][ks] = bf16x8{0, 0, 0, 0, 0, 0, 0, 0};
    }
  }

  uint4 bpre[NB];
  auto loadB = [&](int ks) {
    int kk = k0 + ks * 32;
    #pragma unroll
    for (int i0 = 0; i0 < NB; i0++) {
      int idx = tid + i0 * 256;
      bpre[i0] = make_uint4(0, 0, 0, 0);
      if (idx < CT * 64) {
        int nn = idx >> 2, kc = idx & 3;
        if (kk + kc * 8 < kend)
          bpre[i0] = *(const uint4*)(Wz + (size_t)(n0 + nn) * ldw + kk + kc * 8);
      }
    }
  };
  loadB(0);

  for (int ks = 0; ks < KSTEPS; ks++) {
    __syncthreads();
    #pragma unroll
    for (int i0 = 0; i0 < NB; i0++) {
      int idx = tid + i0 * 256;
      if (idx < CT * 64) {
        int nn = idx >> 2, kc = idx & 3;
        *(uint4*)&Bs[nn * 56 + (((kc ^ (nn & 3)) << 3))] = bpre[i0];
      }
    }
    __syncthreads();
    if (ks + 1 < KSTEPS) loadB(ks + 1);
    #pragma unroll
    for (int ct = 0; ct < CT; ct++) {
      bf16x8 bb = *(const bf16x8*)&Bs[(ct * 16 + r) * 56 + (((g ^ (r & 3)) << 3))];
      #pragma unroll
      for (int rt = 0; rt < RT; rt++)
        acc[rt][ct] = __builtin_amdgcn_mfma_f32_16x16x32_bf16(a_all[rt][ks], bb, acc[rt][ct], 0, 0, 0);
    }
  }

  if (vbt && z == 2) {
    // transposed V epilogue: vbt[((b*8+hh)*80 + feat)*1024 + t]
    #pragma unroll
    for (int rt = 0; rt < RT; rt++) {
      #pragma unroll
      for (int ct = 0; ct < CT; ct++) {
        int feat = ct * 16 + r;
        if (feat < 76) {
          int token = m0 + (w * RT + rt) * 16 + g * 4;
          int bb_ = token >> 10, tt = token & 1023;
          ushort4 pk;
          pk.x = f2b(acc[rt][ct][0]); pk.y = f2b(acc[rt][ct][1]);
          pk.z = f2b(acc[rt][ct][2]); pk.w = f2b(acc[rt][ct][3]);
          *(ushort4*)(vbt + (((size_t)(bb_ * 8 + blockIdx.x) * 80 + feat) << 10) + tt) = pk;
        }
      }
    }
  } else {
    #pragma unroll
    for (int rt = 0; rt < RT; rt++) {
      #pragma unroll
      for (int ct = 0; ct < CT; ct++) {
        int col = n0 + ct * 16 + r;
        if (col < ldc) {
          #pragma unroll
          for (int reg = 0; reg < 4; reg++) {
            int row = m0 + (w * RT + rt) * 16 + g * 4 + reg;
            float val = acc[rt][ct][reg];
            if (bias_eff && col < N) val += bias_eff[col];
            if (RELU) val = fmaxf(val, 0.f);
            Cz[(size_t)row * ldc + col] = f2b(val);
          }
        }
      }
    }
  }
}

// =================== flash attention: swapped QK^T / swapped PV, O^T in-lane stats ========
__global__ __launch_bounds__(256, 3) void attn_kernel(const u16* __restrict__ q,
                                                      const u16* __restrict__ k,
                                                      const u16* __restrict__ vbt,
                                                      u16* __restrict__ att) {
  __shared__ u16 Ks[64 * 104];    // K tile [kv][feat 96], chunk-XOR swizzle
  __shared__ u16 Vt[80 * 72];     // V^T tile [feat 80][kv 64], chunk-XOR swizzle
  __shared__ u16 Ps[128 * 72];    // P [q-row 128][kv 64], dword-XOR swizzle, wave-private rows
  unsigned* Psw = (unsigned*)Ps;
  const int qt = blockIdx.x, hh = blockIdx.y, b = blockIdx.z;
  const int tid = threadIdx.x;
  const int w = tid >> 6, lane = tid & 63;
  const int r = lane & 15, g = lane >> 4;
  const int qbase = b * T_ + qt * 128;
  const float SCL2 = 0.11470786693528088f * 1.4426950408889634f;  // 1/sqrt(76)*log2(e)

  // ---- Q B-fragments direct from global (cols 76..79 are exact zeros; 80..95 masked) ----
  bf16x8 aq[2][3];
  #pragma unroll
  for (int rt = 0; rt < 2; rt++) {
    const u16* src = q + (size_t)(qbase + w * 32 + rt * 16 + r) * QKLD_ + hh * 80;
    #pragma unroll
    for (int ks = 0; ks < 3; ks++) {
      int e0 = ks * 32 + g * 8;
      if (e0 < 80) aq[rt][ks] = *(const bf16x8*)(src + e0);
      else aq[rt][ks] = bf16x8{0, 0, 0, 0, 0, 0, 0, 0};
    }
  }

  // ---- staging (T14: load-early / write-late) ----
  const int krow = tid >> 2, kq4 = tid & 3;
  uint4 kpre[3], vpre[3];
  auto stage_load = [&](int kt) {
    int kbase = b * T_ + kt * 64;
    const u16* ksrc = k + (size_t)(kbase + krow) * QKLD_ + hh * 80;
    #pragma unroll
    for (int i = 0; i < 3; i++) {
      int c = kq4 + 4 * i;
      kpre[i] = (c < 10) ? *(const uint4*)(ksrc + c * 8) : make_uint4(0, 0, 0, 0);
    }
    const u16* vsrc = vbt + ((size_t)(b * 8 + hh) * 80) * 1024 + kbase;
    #pragma unroll
    for (int p = 0; p < 3; p++) {
      int idx = tid + p * 256;
      vpre[p] = (idx < 640) ? *(const uint4*)(vsrc + (size_t)(idx >> 3) * 1024 + (idx & 7) * 8)
                            : make_uint4(0, 0, 0, 0);
    }
  };
  auto stage_write = [&]() {
    #pragma unroll
    for (int i = 0; i < 3; i++) {
      int c = kq4 + 4 * i;
      *(uint4*)&Ks[kidx(krow, c * 8)] = kpre[i];
    }
    #pragma unroll
    for (int p = 0; p < 3; p++) {
      int idx = tid + p * 256;
      if (idx < 640) {
        int f = idx >> 3, ch = idx & 7;
        *(uint4*)&Vt[f * 72 + ((ch ^ (f & 3)) << 3)] = vpre[p];
      }
    }
  };

  const f32x4 fz = {0.f, 0.f, 0.f, 0.f};
  f32x4 o[2][5];
  float m2[2], ls[2];
  #pragma unroll
  for (int rt = 0; rt < 2; rt++) {
    #pragma unroll
    for (int i = 0; i < 5; i++) o[rt][i] = fz;
    m2[rt] = -INFINITY; ls[rt] = 0.f;
  }

  stage_load(0);
  for (int kt = 0; kt < 16; kt++) {
    __syncthreads();
    stage_write();
    __syncthreads();
    if (kt < 15) stage_load(kt + 1);

    // ---- S^T = K Q (lane holds 16 kv-values for one q-row) ----
    f32x4 st[2][4];
    #pragma unroll
    for (int ct = 0; ct < 4; ct++) { st[0][ct] = fz; st[1][ct] = fz; }
    #pragma unroll
    for (int ct = 0; ct < 4; ct++) {
      #pragma unroll
      for (int ks = 0; ks < 3; ks++) {
        bf16x8 ak = *(const bf16x8*)&Ks[kidx(ct * 16 + r, (ks * 4 + g) * 8)];
        st[0][ct] = __builtin_amdgcn_mfma_f32_16x16x32_bf16(ak, aq[0][ks], st[0][ct], 0, 0, 0);
        st[1][ct] = __builtin_amdgcn_mfma_f32_16x16x32_bf16(ak, aq[1][ks], st[1][ct], 0, 0, 0);
      }
    }

    // ---- online softmax: in-lane tree + 2 shfls; P packed into LDS dwords ----
    #pragma unroll
    for (int rt = 0; rt < 2; rt++) {
      float xs[4][4];
      float mx = -INFINITY;
      #pragma unroll
      for (int ct = 0; ct < 4; ct++) {
        #pragma unroll
        for (int e = 0; e < 4; e++) {
          xs[ct][e] = st[rt][ct][e] * SCL2;
          mx = fmaxf(mx, xs[ct][e]);
        }
      }
      mx = fmaxf(mx, __shfl_xor(mx, 16));
      mx = fmaxf(mx, __shfl_xor(mx, 32));
      float nm = fmaxf(m2[rt], mx);
      float alpha = exp2f(m2[rt] - nm);
      m2[rt] = nm;
      float rs = 0.f;
      u32 pk[4][2];
      #pragma unroll
      for (int ct = 0; ct < 4; ct++) {
        float p0 = exp2f(xs[ct][0] - nm), p1 = exp2f(xs[ct][1] - nm);
        float p2 = exp2f(xs[ct][2] - nm), p3 = exp2f(xs[ct][3] - nm);
        rs += (p0 + p1) + (p2 + p3);
        pk[ct][0] = pack2(p0, p1);
        pk[ct][1] = pack2(p2, p3);
      }
      rs += __shfl_xor(rs, 16);
      rs += __shfl_xor(rs, 32);
      ls[rt] = ls[rt] * alpha + rs;
      #pragma unroll
      for (int c5 = 0; c5 < 5; c5++) o[rt][c5] *= alpha;
      // write P: row = w*32+rt*16+r, kv-dword = ct*8+g*2 (+h), XOR mask (r&3)<<2
      unsigned* pw = Psw + (size_t)(w * 32 + rt * 16 + r) * 36;
      #pragma unroll
      for (int ct = 0; ct < 4; ct++) {
        int dw = (ct * 8 + g * 2) ^ ((r & 3) << 2);
        *(uint2*)(pw + dw) = make_uint2(pk[ct][0], pk[ct][1]);
      }
    }

    // ---- O^T += V^T P  (A = V^T frag, B = P frag) ----
    bf16x8 pa[2][2];
    #pragma unroll
    for (int rt = 0; rt < 2; rt++) {
      const unsigned* pr = Psw + (size_t)(w * 32 + rt * 16 + r) * 36;
      #pragma unroll
      for (int ks = 0; ks < 2; ks++) {
        uint4 t = *(const uint4*)(pr + (ks * 16 + ((g ^ (r & 3)) << 2)));
        pa[rt][ks] = *reinterpret_cast<bf16x8*>(&t);
      }
    }
    #pragma unroll
    for (int ks = 0; ks < 2; ks++) {
      #pragma unroll
      for (int c5 = 0; c5 < 5; c5++) {
        int f = c5 * 16 + r;
        bf16x8 bv = *(const bf16x8*)&Vt[f * 72 + (((ks * 4 + g) ^ (f & 3)) << 3)];
        #pragma unroll
        for (int rt = 0; rt < 2; rt++)
          o[rt][c5] = __builtin_amdgcn_mfma_f32_16x16x32_bf16(bv, pa[rt][ks], o[rt][c5], 0, 0, 0);
      }
    }
  }

  // ---- write O: lane holds feats g*4+e (tile c5) for q-row r ----
  #pragma unroll
  for (int rt = 0; rt < 2; rt++) {
    float inv = 1.f / ls[rt];
    int token = qbase + w * 32 + rt * 16 + r;
    #pragma unroll
    for (int c5 = 0; c5 < 5; c5++) {
      if (c5 == 4 && g == 3) continue;
      ushort4 pk;
      pk.x = f2b(o[rt][c5][0] * inv);
      pk.y = f2b(o[rt][c5][1] * inv);
      pk.z = f2b(o[rt][c5][2] * inv);
      pk.w = f2b(o[rt][c5][3] * inv);
      *(ushort4*)&att[(size_t)token * HK_ + hh * 76 + c5 * 16 + g * 4] = pk;
    }
  }
}

// =================== fused (x0 + x1 + res) + LayerNorm -> bf16 (u32-vectorized) ===========
__global__ __launch_bounds__(256) void ln_kernel(const u16* __restrict__ x0,
                                                 const u16* __restrict__ x1,
                                                 const u16* __restrict__ res,
                                                 const float* __restrict__ sc,
                                                 const float* __restrict__ bb,
                                                 u16* __restrict__ out) {
  int w = threadIdx.x >> 6, lane = threadIdx.x & 63;
  int row = blockIdx.x * 4 + w;
  const unsigned* p0 = (const unsigned*)(x0 + (size_t)row * KP_);
  const unsigned* p1 = (const unsigned*)(x1 + (size_t)row * KP_);
  const unsigned* p2 = (const unsigned*)(res + (size_t)row * KP_);
  float lo = 0.f, hi = 0.f;
  if (lane < 38) {
    unsigned a = p0[lane], c = p1[lane], d = p2[lane];
    lo = b2f((u16)(a & 0xffff)) + b2f((u16)(c & 0xffff)) + b2f((u16)(d & 0xffff));
    hi = b2f((u16)(a >> 16)) + b2f((u16)(c >> 16)) + b2f((u16)(d >> 16));
  }
  float sum = lo + hi;
  #pragma unroll
  for (int m = 1; m < 64; m <<= 1) sum += __shfl_xor(sum, m);
  float mu = sum * (1.f / 76.f);
  float dlo = (lane < 38) ? lo - mu : 0.f;
  float dhi = (lane < 38) ? hi - mu : 0.f;
  float var = dlo * dlo + dhi * dhi;
  #pragma unroll
  for (int m = 1; m < 64; m <<= 1) var += __shfl_xor(var, m);
  float rstd = rsqrtf(var * (1.f / 76.f) + EPS_);
  if (lane < 48) {
    unsigned ow = 0;
    if (lane < 38) {
      float2 s2 = *(const float2*)(sc + 2 * lane);
      float2 b2 = *(const float2*)(bb + 2 * lane);
      ow = pack2(dlo * rstd * s2.x + b2.x, dhi * rstd * s2.y + b2.y);
    }
    ((unsigned*)(out + (size_t)row * KP_))[lane] = ow;
  }
}

// =================== output projection 76 -> 2, fp32 out ===========
__global__ void out_kernel(const u16* __restrict__ h, const float* __restrict__ W,
                           const float* __restrict__ bias, float* __restrict__ out) {
  int idx = blockIdx.x * 256 + threadIdx.x;
  if (idx >= BT_ * C_) return;
  int bt = idx >> 1, c = idx & 1;
  float acc = bias[c];
  const u16* hr = h + (size_t)bt * KP_;
  #pragma unroll 4
  for (int e = 0; e < K_; e++) acc += b2f(hr[e]) * W[e * C_ + c];
  out[idx] = acc;
}

extern "C" void kernel_launch(void* const* d_in, const int* in_sizes, int n_in,
                              void* d_out, int out_size, void* d_ws, size_t ws_size,
                              hipStream_t stream) {
  const float* v    = (const float*)d_in[0];
  const float* x    = (const float*)d_in[1];
  const float* y    = (const float*)d_in[2];
  const float* z    = (const float*)d_in[3];
  const float* W_hp = (const float*)d_in[4];
  const float* b_hp = (const float*)d_in[5];
  const float* W_lm = (const float*)d_in[6];
  const float* b_lm = (const float*)d_in[7];
  const float* W_el = (const float*)d_in[8];
  const float* b_el = (const float*)d_in[9];
  const float* W_au = (const float*)d_in[10];
  const float* b_au = (const float*)d_in[11];
  const float* pos  = (const float*)d_in[12];
  const float* Wq   = (const float*)d_in[13];
  const float* Wk   = (const float*)d_in[14];
  const float* Wv   = (const float*)d_in[15];
  const float* Wu   = (const float*)d_in[16];
  const float* bu   = (const float*)d_in[17];
  const float* ln1s = (const float*)d_in[18];
  const float* ln1b = (const float*)d_in[19];
  const float* W1   = (const float*)d_in[20];
  const float* b1   = (const float*)d_in[21];
  const float* W2   = (const float*)d_in[22];
  const float* b2   = (const float*)d_in[23];
  const float* ln2s = (const float*)d_in[24];
  const float* ln2b = (const float*)d_in[25];
  const float* Wout = (const float*)d_in[26];
  const float* bout = (const float*)d_in[27];

  u16* ws  = (u16*)d_ws;
  u16* WT  = ws;                          // 6*304128 = 1824768
  u16* h   = WT + 1824768;                // 8192*96
  u16* qb  = h + 786432;                  // 8192*640
  u16* kb  = qb + 5242880;                // 8192*640
  u16* vbt = kb + 5242880;                // 64*80*1024 (transposed V)
  u16* att = vbt + 5242880;               // 8192*608
  // aliases (dead-buffer reuse):
  u16* u0  = kb;                          // Wu out, split-K half 0
  u16* u1  = kb + 786432;                 // half 1
  u16* h1  = kb + 1572864;                // LN1 out
  u16* ff  = att;                         // W1 out (att dead after Wu)
  u16* f20 = qb;                          // W2 half 0 (qb dead after attn)
  u16* f21 = qb + 786432;                 // half 1

  wconv_kernel<<<dim3(30, 36), 256, 0, stream>>>(Wq, Wk, Wv, Wu, W1, W2, WT);
  embed_kernel<<<(BT_ * KP_ + 255) / 256, 256, 0, stream>>>(
      v, x, y, z, W_hp, b_hp, W_lm, b_lm, W_el, b_el, W_au, b_au, pos, h);

  for (int d = 0; d < D_; d++) {
    u16* WTd = WT + (size_t)d * PER_L_;
    const float* bu_d = bu + (size_t)d * K_;
    const float* l1s  = ln1s + (size_t)d * K_;
    const float* l1b  = ln1b + (size_t)d * K_;
    const float* b1_d = b1 + (size_t)d * FF_;
    const float* b2_d = b2 + (size_t)d * K_;
    const float* l2s  = ln2s + (size_t)d * K_;
    const float* l2b  = ln2b + (size_t)d * K_;

    // QKV: z=0,1 -> qb,kb (row-major, head stride 80); z=2 -> vbt (transposed)
    gemm_kernel<2, 5, 3, 0><<<dim3(8, 64, 3), 256, 0, stream>>>(
        h, KP_, WTd, KP_, 61440ULL, nullptr, qb, QKLD_, QKLD_, 0, KP_, 5242880ULL, vbt);
    attn_kernel<<<dim3(8, 8, 8), 256, 0, stream>>>(qb, kb, vbt, att);
    // Wu: split-K=2 over 608 -> u0,u1
    gemm_kernel<1, 6, 10, 0><<<dim3(1, 128, 2), 256, 0, stream>>>(
        att, HK_, WTd + 184320, HK_, 0ULL, bu_d, u0, KP_, K_, 304, 304, 786432ULL, nullptr);
    ln_kernel<<<BT_ / 4, 256, 0, stream>>>(u0, u1, h, l1s, l1b, h1);
    // W1 (+relu)
    gemm_kernel<2, 5, 3, 1><<<dim3(4, 64, 1), 256, 0, stream>>>(
        h1, KP_, WTd + 242688, KP_, 0ULL, b1_d, ff, FFP_, FF_, 0, KP_, 0ULL, nullptr);
    // W2: split-K=2 over 320 -> f20,f21
    gemm_kernel<1, 6, 5, 0><<<dim3(1, 128, 2), 256, 0, stream>>>(
        ff, FFP_, WTd + 273408, FFP_, 0ULL, b2_d, f20, KP_, K_, 160, 160, 786432ULL, nullptr);
    ln_kernel<<<BT_ / 4, 256, 0, stream>>>(f20, f21, h1, l2s, l2b, h);
  }

  out_kernel<<<(BT_ * C_ + 255) / 256, 256, 0, stream>>>(h, Wout, bout, (float*)d_out);
}